// Round 1
// baseline (22618.918 us; speedup 1.0000x reference)
//
#include <hip/hip_runtime.h>
#include <cstdio>
#include <cmath>

#define HIDDEN 768
#define HEADS 8
#define DHEAD 96
#define NLAYERS 2

// ---------------------------------------------------------------- GEMM (f32)
// C[M,N] = act(A[M,K] @ W[K,N] + bias), optional batch (blockIdx.z) with
// element strides sA/sW/sB/sC. 64x64 tile, BK=16, 256 threads, 4x4 per thread.
template<int ACT>
__global__ void gemm_f32(const float* __restrict__ A, int lda, long sA,
                         const float* __restrict__ W, int ldw, long sW,
                         const float* __restrict__ bias, long sB,
                         float* __restrict__ C, int ldc, long sC,
                         int M, int N, int K)
{
    int bz = blockIdx.z;
    A += (long)bz * sA;
    W += (long)bz * sW;
    C += (long)bz * sC;
    if (bias) bias += (long)bz * sB;

    __shared__ float As[16][65];   // [k][m], +1 pad
    __shared__ float Ws[16][65];   // [k][n], +1 pad

    int tid = threadIdx.x;
    int tx = tid & 15;   // N direction
    int ty = tid >> 4;   // M direction
    int m0 = blockIdx.x * 64;
    int n0 = blockIdx.y * 64;

    float acc[4][4] = {};

    for (int k0 = 0; k0 < K; k0 += 16) {
        #pragma unroll
        for (int i = 0; i < 4; i++) {          // A tile: 64 rows x 16 k
            int t = tid + i * 256;
            int mm = t >> 4, kk = t & 15;
            int gm = m0 + mm;
            As[kk][mm] = (gm < M) ? A[(long)gm * lda + (k0 + kk)] : 0.f;
        }
        #pragma unroll
        for (int i = 0; i < 4; i++) {          // W tile: 16 k x 64 n
            int t = tid + i * 256;
            int kk = t >> 6, nn = t & 63;
            int gn = n0 + nn;
            Ws[kk][nn] = (gn < N) ? W[(long)(k0 + kk) * ldw + gn] : 0.f;
        }
        __syncthreads();
        #pragma unroll
        for (int kk = 0; kk < 16; kk++) {
            float a[4], w[4];
            #pragma unroll
            for (int i = 0; i < 4; i++) a[i] = As[kk][ty * 4 + i];
            #pragma unroll
            for (int j = 0; j < 4; j++) w[j] = Ws[kk][tx * 4 + j];
            #pragma unroll
            for (int i = 0; i < 4; i++)
                #pragma unroll
                for (int j = 0; j < 4; j++)
                    acc[i][j] = fmaf(a[i], w[j], acc[i][j]);
        }
        __syncthreads();
    }

    #pragma unroll
    for (int i = 0; i < 4; i++) {
        int gm = m0 + ty * 4 + i;
        if (gm >= M) continue;
        #pragma unroll
        for (int j = 0; j < 4; j++) {
            int gn = n0 + tx * 4 + j;
            if (gn >= N) continue;
            float v = acc[i][j];
            if (bias) v += bias[gn];
            if (ACT == 1) v = fmaxf(v, 0.f);
            C[(long)gm * ldc + gn] = v;
        }
    }
}

// ---------------------------------------------------------------- utility
__global__ void fill_f32(float* __restrict__ p, float v, long n) {
    long i = blockIdx.x * (long)blockDim.x + threadIdx.x;
    if (i < n) p[i] = v;
}

__global__ void gelu_k(const float* __restrict__ in, float* __restrict__ out, long n) {
    long i = blockIdx.x * (long)blockDim.x + threadIdx.x;
    if (i < n) {
        float x = in[i];
        out[i] = 0.5f * x * (1.f + erff(x * 0.70710678118654752f));
    }
}

// out = relu(beta*o + (1-beta)*h), beta = sigmoid(sp[0])
__global__ void skip_k(const float* __restrict__ o, const float* __restrict__ hin,
                       const float* __restrict__ sp, float* __restrict__ out, long n) {
    long i = blockIdx.x * (long)blockDim.x + threadIdx.x;
    if (i < n) {
        float beta = 1.f / (1.f + expf(-sp[0]));
        float v = beta * o[i] + (1.f - beta) * hin[i];
        out[i] = fmaxf(v, 0.f);
    }
}

// ---------------------------------------------------------------- edge ops
// logits[e,h] = dot(q[dst[e],h,:], kt[src[e],h,:]) * pR[h] / sqrt(96)
__global__ void edge_logits(const float* __restrict__ q, const float* __restrict__ kt,
                            const int* __restrict__ src, const int* __restrict__ dst,
                            const float* __restrict__ prel, float* __restrict__ out,
                            int ne)
{
    int idx = blockIdx.x * blockDim.x + threadIdx.x;
    if (idx >= ne * HEADS) return;
    int e = idx >> 3;
    int h = idx & 7;
    const float* qr = q  + (long)dst[e] * HIDDEN + h * DHEAD;
    const float* kr = kt + (long)src[e] * HIDDEN + h * DHEAD;
    float s = 0.f;
    #pragma unroll 8
    for (int d = 0; d < DHEAD; d++) s = fmaf(qr[d], kr[d], s);
    out[idx] = s * prel[h] * 0.1020620726159658f;   // 1/sqrt(96)
}

__device__ __forceinline__ void atomicMaxF(float* addr, float val) {
    int* ia = (int*)addr;
    int cur = __float_as_int(*addr);
    while (__int_as_float(cur) < val) {
        int assumed = cur;
        cur = atomicCAS(ia, assumed, __float_as_int(val));
        if (cur == assumed) break;
    }
}

__global__ void seg_max_k(const float* __restrict__ lg, const int* __restrict__ dst,
                          float* __restrict__ dmax, int ne) {
    int idx = blockIdx.x * blockDim.x + threadIdx.x;
    if (idx >= ne * HEADS) return;
    int e = idx >> 3, h = idx & 7;
    atomicMaxF(&dmax[(long)dst[e] * HEADS + h], lg[idx]);
}

__global__ void seg_expsum_k(float* __restrict__ lg, const int* __restrict__ dst,
                             const float* __restrict__ dmax, float* __restrict__ denom,
                             int ne) {
    int idx = blockIdx.x * blockDim.x + threadIdx.x;
    if (idx >= ne * HEADS) return;
    int e = idx >> 3, h = idx & 7;
    float v = expf(lg[idx] - dmax[(long)dst[e] * HEADS + h]);
    lg[idx] = v;
    atomicAdd(&denom[(long)dst[e] * HEADS + h], v);
}

__global__ void seg_norm_k(float* __restrict__ lg, const int* __restrict__ dst,
                           const float* __restrict__ denom, int ne) {
    int idx = blockIdx.x * blockDim.x + threadIdx.x;
    if (idx >= ne * HEADS) return;
    int e = idx >> 3, h = idx & 7;
    lg[idx] = lg[idx] / (denom[(long)dst[e] * HEADS + h] + 1e-16f);
}

// aggr[dst[e], c] += alpha[e, c/96] * vt[src[e], c]
__global__ void edge_accum(const float* __restrict__ alpha, const float* __restrict__ vt,
                           const int* __restrict__ src, const int* __restrict__ dst,
                           float* __restrict__ aggr, int ne)
{
    long idx = blockIdx.x * (long)blockDim.x + threadIdx.x;
    if (idx >= (long)ne * HIDDEN) return;
    int e = (int)(idx / HIDDEN);
    int c = (int)(idx % HIDDEN);
    int h = c / DHEAD;
    float a = alpha[(long)e * HEADS + h];
    float v = vt[(long)src[e] * HIDDEN + c];
    atomicAdd(&aggr[(long)dst[e] * HIDDEN + c], a * v);
}

// ---------------------------------------------------------------- host
static inline void launch_gemm(hipStream_t stream,
                               const float* A, int lda, long sA,
                               const float* W, int ldw, long sW,
                               const float* bias, long sB,
                               float* C, int ldc, long sC,
                               int M, int N, int K, int batch, int act)
{
    dim3 grid((M + 63) / 64, (N + 63) / 64, batch);
    dim3 block(256);
    if (act)
        gemm_f32<1><<<grid, block, 0, stream>>>(A, lda, sA, W, ldw, sW, bias, sB, C, ldc, sC, M, N, K);
    else
        gemm_f32<0><<<grid, block, 0, stream>>>(A, lda, sA, W, ldw, sW, bias, sB, C, ldc, sC, M, N, K);
}

extern "C" void kernel_launch(void* const* d_in, const int* in_sizes, int n_in,
                              void* d_out, int out_size, void* d_ws, size_t ws_size,
                              hipStream_t stream)
{
    const float* x0  = (const float*)d_in[0];
    const float* x1  = (const float*)d_in[1];
    const float* nlW = (const float*)d_in[2];
    const float* nlb = (const float*)d_in[3];
    const float* kW  = (const float*)d_in[4];   // [L,2,4,768,768]
    const float* kb  = (const float*)d_in[5];   // [L,2,4,768]
    const float* skp = (const float*)d_in[6];   // [L,2]
    const float* aR  = (const float*)d_in[7];   // [L,3,8,96,96]
    const float* mR  = (const float*)d_in[8];   // [L,3,8,96,96]
    const float* pR  = (const float*)d_in[9];   // [L,3,8]
    const int* esrc[3] = {(const int*)d_in[10], (const int*)d_in[12], (const int*)d_in[14]};
    const int* edst[3] = {(const int*)d_in[11], (const int*)d_in[13], (const int*)d_in[15]};
    const int EST[3] = {0, 1, 0};
    const int EDT[3] = {0, 0, 1};
    const int EN[3]  = {in_sizes[10], in_sizes[12], in_sizes[14]};

    const int NP = in_sizes[0] / HIDDEN;
    const int NA = in_sizes[1] / HIDDEN;
    const int ns[2] = {NP, NA};

    // ---- workspace layout (f32, phased to keep peak ~812 MB) ----
    float* base = (float*)d_ws;
    size_t off = 0;
    auto alloc = [&](size_t n) { float* r = base + off; off += (n + 63) & ~(size_t)63; return r; };
    float* h[2]      = { alloc((size_t)NP * HIDDEN), alloc((size_t)NA * HIDDEN) };
    float* bufKVO[2] = { alloc((size_t)NP * HIDDEN), alloc((size_t)NA * HIDDEN) }; // K -> V -> O
    float* bufQA[2]  = { alloc((size_t)NP * HIDDEN), alloc((size_t)NA * HIDDEN) }; // Q -> aggr
    float* R5        = alloc((size_t)NP * HIDDEN);                                 // kt / vt / gelu
    float* alphab[3];
    for (int e = 0; e < 3; e++) alphab[e] = alloc((size_t)EN[e] * HEADS);
    float* dmax  = alloc((size_t)NP * HEADS);
    float* denom = alloc((size_t)NP * HEADS);
    if (off * sizeof(float) > ws_size) {
        fprintf(stderr, "kernel_launch: ws too small: need %zu have %zu\n",
                off * sizeof(float), ws_size);
    }

    // ---- input projection + relu ----
    launch_gemm(stream, x0, HIDDEN, 0, nlW, HIDDEN, 0, nlb, 0,
                h[0], HIDDEN, 0, NP, HIDDEN, HIDDEN, 1, 1);
    launch_gemm(stream, x1, HIDDEN, 0, nlW + (size_t)HIDDEN * HIDDEN, HIDDEN, 0, nlb + HIDDEN, 0,
                h[1], HIDDEN, 0, NA, HIDDEN, HIDDEN, 1, 1);

    for (int l = 0; l < NLAYERS; l++) {
        // ---- phase A: K,Q projections; per-edge-type logits + segment softmax ----
        for (int t = 0; t < 2; t++) {
            size_t wb = ((size_t)l * 2 + t) * 4;
            launch_gemm(stream, h[t], HIDDEN, 0, kW + (wb + 0) * HIDDEN * HIDDEN, HIDDEN, 0,
                        kb + (wb + 0) * HIDDEN, 0, bufKVO[t], HIDDEN, 0, ns[t], HIDDEN, HIDDEN, 1, 0);
            launch_gemm(stream, h[t], HIDDEN, 0, kW + (wb + 1) * HIDDEN * HIDDEN, HIDDEN, 0,
                        kb + (wb + 1) * HIDDEN, 0, bufQA[t], HIDDEN, 0, ns[t], HIDDEN, HIDDEN, 1, 0);
        }
        for (int e = 0; e < 3; e++) {
            int st = EST[e], dt = EDT[e], Ne = EN[e];
            // kt = k[st] @ aR  (head-batched [N,96]@[96,96])
            const float* aW = aR + ((size_t)l * 3 + e) * HEADS * DHEAD * DHEAD;
            launch_gemm(stream, bufKVO[st], HIDDEN, DHEAD, aW, DHEAD, (long)DHEAD * DHEAD,
                        nullptr, 0, R5, HIDDEN, DHEAD, ns[st], DHEAD, DHEAD, HEADS, 0);
            int nthr = Ne * HEADS;
            edge_logits<<<(nthr + 255) / 256, 256, 0, stream>>>(
                bufQA[dt], R5, esrc[e], edst[e], pR + ((size_t)l * 3 + e) * HEADS, alphab[e], Ne);
            long nd = (long)ns[dt] * HEADS;
            fill_f32<<<(int)((nd + 255) / 256), 256, 0, stream>>>(dmax, -INFINITY, nd);
            hipMemsetAsync(denom, 0, nd * sizeof(float), stream);
            seg_max_k<<<(nthr + 255) / 256, 256, 0, stream>>>(alphab[e], edst[e], dmax, Ne);
            seg_expsum_k<<<(nthr + 255) / 256, 256, 0, stream>>>(alphab[e], edst[e], dmax, denom, Ne);
            seg_norm_k<<<(nthr + 255) / 256, 256, 0, stream>>>(alphab[e], edst[e], denom, Ne);
        }
        // ---- phase B: V projection (reuse K buffers), weighted scatter-add ----
        for (int t = 0; t < 2; t++) {
            size_t wb = ((size_t)l * 2 + t) * 4;
            launch_gemm(stream, h[t], HIDDEN, 0, kW + (wb + 2) * HIDDEN * HIDDEN, HIDDEN, 0,
                        kb + (wb + 2) * HIDDEN, 0, bufKVO[t], HIDDEN, 0, ns[t], HIDDEN, HIDDEN, 1, 0);
            hipMemsetAsync(bufQA[t], 0, (size_t)ns[t] * HIDDEN * sizeof(float), stream);
        }
        for (int e = 0; e < 3; e++) {
            int st = EST[e], dt = EDT[e];
            const float* mW = mR + ((size_t)l * 3 + e) * HEADS * DHEAD * DHEAD;
            launch_gemm(stream, bufKVO[st], HIDDEN, DHEAD, mW, DHEAD, (long)DHEAD * DHEAD,
                        nullptr, 0, R5, HIDDEN, DHEAD, ns[st], DHEAD, DHEAD, HEADS, 0);
            long tot = (long)EN[e] * HIDDEN;
            edge_accum<<<(int)((tot + 255) / 256), 256, 0, stream>>>(
                alphab[e], R5, esrc[e], edst[e], bufQA[dt], EN[e]);
        }
        // ---- phase C: gelu -> A-projection -> skip/relu ----
        for (int t = 0; t < 2; t++) {
            size_t wb = ((size_t)l * 2 + t) * 4;
            long n = (long)ns[t] * HIDDEN;
            gelu_k<<<(int)((n + 255) / 256), 256, 0, stream>>>(bufQA[t], R5, n);
            launch_gemm(stream, R5, HIDDEN, 0, kW + (wb + 3) * HIDDEN * HIDDEN, HIDDEN, 0,
                        kb + (wb + 3) * HIDDEN, 0, bufKVO[t], HIDDEN, 0, ns[t], HIDDEN, HIDDEN, 1, 0);
            float* outp = (l == NLAYERS - 1)
                        ? ((float*)d_out + (t == 0 ? 0 : (size_t)NP * HIDDEN))
                        : h[t];
            skip_k<<<(int)((n + 255) / 256), 256, 0, stream>>>(
                bufKVO[t], h[t], skp + l * 2 + t, outp, n);
        }
    }
}

// Round 2
// 5343.444 us; speedup vs baseline: 4.2330x; 4.2330x over previous
//
#include <hip/hip_runtime.h>
#include <cstdio>
#include <cmath>

#define HIDDEN 768
#define HEADS 8
#define DHEAD 96
#define NLAYERS 2
#define HH (HIDDEN * HIDDEN)

typedef unsigned short u16;
typedef unsigned int u32;
typedef __attribute__((ext_vector_type(8))) short bf16x8;
typedef __attribute__((ext_vector_type(4))) float f32x4;

__device__ __forceinline__ u16 f2b(float f) {
    u32 u = __float_as_uint(f);
    u32 r = (u + 0x7FFFu + ((u >> 16) & 1u)) >> 16;
    return (u16)r;
}
__device__ __forceinline__ float b2f(u16 v) { return __uint_as_float(((u32)v) << 16); }

// ================================================================== MFMA GEMM
// C[M,N] = act(A[M,K] @ Wt[N,K]^T + bias). A, Wt bf16 (u16) row-major,
// K contiguous for both. M multiple of 128, N multiple of 128, K multiple of 32.
// 128x128 tile, BK=32, 256 threads (4 waves, 2x2 of 64x64), 16x16x32 MFMA.
// LDS chunk swizzle s(r)=(r>>1)&3 keeps frag reads at 2-way (free).
template<int OUTF, int OUTB, int ACT>
__global__ __launch_bounds__(256, 3)
void gemm_mfma(const u16* __restrict__ A, const u16* __restrict__ Wt,
               const float* __restrict__ bias,
               float* __restrict__ Cf, u16* __restrict__ Cb,
               int M, int N, int K)
{
    __shared__ u16 As[128 * 32];
    __shared__ u16 Bs[128 * 32];
    const int tid = threadIdx.x;
    const int lane = tid & 63;
    const int wave = tid >> 6;
    const long m0 = (long)blockIdx.x * 128;
    const long n0 = (long)blockIdx.y * 128;
    const int wm = (wave & 1) * 64;
    const int wn = (wave >> 1) * 64;

    f32x4 acc[4][4];
#pragma unroll
    for (int i = 0; i < 4; i++)
#pragma unroll
        for (int j = 0; j < 4; j++) acc[i][j] = (f32x4){0.f, 0.f, 0.f, 0.f};

    // staging map: ci in {tid, tid+256}; row r=ci>>2, lds pos p=ci&3,
    // global chunk g = p ^ ((r>>1)&3)
    const int r0 = tid >> 2, p0 = tid & 3;
    const int g0 = p0 ^ ((r0 >> 1) & 3);
    const int r1 = r0 + 64;
    const int g1 = p0 ^ ((r1 >> 1) & 3);
    const u16* ga0 = A + (m0 + r0) * (long)K + g0 * 8;
    const u16* ga1 = A + (m0 + r1) * (long)K + g1 * 8;
    const u16* gb0 = Wt + (n0 + r0) * (long)K + g0 * 8;
    const u16* gb1 = Wt + (n0 + r1) * (long)K + g1 * 8;
    u16* la0 = As + tid * 8;
    u16* la1 = As + (tid + 256) * 8;
    u16* lb0 = Bs + tid * 8;
    u16* lb1 = Bs + (tid + 256) * 8;

    for (int k0 = 0; k0 < K; k0 += 32) {
        __builtin_amdgcn_global_load_lds((const __attribute__((address_space(1))) void*)(ga0 + k0),
                                         (__attribute__((address_space(3))) void*)la0, 16, 0, 0);
        __builtin_amdgcn_global_load_lds((const __attribute__((address_space(1))) void*)(ga1 + k0),
                                         (__attribute__((address_space(3))) void*)la1, 16, 0, 0);
        __builtin_amdgcn_global_load_lds((const __attribute__((address_space(1))) void*)(gb0 + k0),
                                         (__attribute__((address_space(3))) void*)lb0, 16, 0, 0);
        __builtin_amdgcn_global_load_lds((const __attribute__((address_space(1))) void*)(gb1 + k0),
                                         (__attribute__((address_space(3))) void*)lb1, 16, 0, 0);
        __syncthreads();

        bf16x8 af[4], bfr[4];
        const int q = lane >> 4;
        const int lr = lane & 15;
#pragma unroll
        for (int i = 0; i < 4; i++) {
            int rr = wm + i * 16 + lr;
            af[i] = *(const bf16x8*)(As + rr * 32 + ((q ^ ((rr >> 1) & 3)) * 8));
            int rn = wn + i * 16 + lr;
            bfr[i] = *(const bf16x8*)(Bs + rn * 32 + ((q ^ ((rn >> 1) & 3)) * 8));
        }
#pragma unroll
        for (int i = 0; i < 4; i++)
#pragma unroll
            for (int j = 0; j < 4; j++)
                acc[i][j] = __builtin_amdgcn_mfma_f32_16x16x32_bf16(af[i], bfr[j], acc[i][j], 0, 0, 0);
        __syncthreads();
    }

    const int lc = lane & 15, lq = lane >> 4;
#pragma unroll
    for (int j = 0; j < 4; j++) {
        long col = n0 + wn + j * 16 + lc;
        float bv = bias ? bias[col] : 0.f;
#pragma unroll
        for (int i = 0; i < 4; i++) {
#pragma unroll
            for (int rg = 0; rg < 4; rg++) {
                long row = m0 + wm + i * 16 + lq * 4 + rg;
                float v = acc[i][j][rg] + bv;
                if (ACT) v = fmaxf(v, 0.f);
                if (OUTF) Cf[row * N + col] = v;
                if (OUTB) Cb[row * N + col] = f2b(v);
            }
        }
    }
}

// ================================================================== f32 GEMM
// (kept for the tiny combined-weight GEMMs: M=768, N=96, K=96, batch=heads)
template<int ACT>
__global__ void gemm_f32(const float* __restrict__ A, int lda, long sA,
                         const float* __restrict__ W, int ldw, long sW,
                         const float* __restrict__ bias, long sB,
                         float* __restrict__ C, int ldc, long sC,
                         int M, int N, int K)
{
    int bz = blockIdx.z;
    A += (long)bz * sA;
    W += (long)bz * sW;
    C += (long)bz * sC;
    if (bias) bias += (long)bz * sB;

    __shared__ float Ash[16][65];
    __shared__ float Wsh[16][65];

    int tid = threadIdx.x;
    int tx = tid & 15, ty = tid >> 4;
    int m0 = blockIdx.x * 64, n0 = blockIdx.y * 64;
    float acc[4][4] = {};

    for (int k0 = 0; k0 < K; k0 += 16) {
#pragma unroll
        for (int i = 0; i < 4; i++) {
            int t = tid + i * 256;
            int mm = t >> 4, kk = t & 15;
            int gm = m0 + mm;
            Ash[kk][mm] = (gm < M) ? A[(long)gm * lda + (k0 + kk)] : 0.f;
        }
#pragma unroll
        for (int i = 0; i < 4; i++) {
            int t = tid + i * 256;
            int kk = t >> 6, nn = t & 63;
            int gn = n0 + nn;
            Wsh[kk][nn] = (gn < N) ? W[(long)(k0 + kk) * ldw + gn] : 0.f;
        }
        __syncthreads();
#pragma unroll
        for (int kk = 0; kk < 16; kk++) {
            float a[4], w[4];
#pragma unroll
            for (int i = 0; i < 4; i++) a[i] = Ash[kk][ty * 4 + i];
#pragma unroll
            for (int j = 0; j < 4; j++) w[j] = Wsh[kk][tx * 4 + j];
#pragma unroll
            for (int i = 0; i < 4; i++)
#pragma unroll
                for (int j = 0; j < 4; j++) acc[i][j] = fmaf(a[i], w[j], acc[i][j]);
        }
        __syncthreads();
    }
#pragma unroll
    for (int i = 0; i < 4; i++) {
        int gm = m0 + ty * 4 + i;
        if (gm >= M) continue;
#pragma unroll
        for (int j = 0; j < 4; j++) {
            int gn = n0 + tx * 4 + j;
            if (gn >= N) continue;
            float v = acc[i][j];
            if (bias) v += bias[gn];
            if (ACT == 1) v = fmaxf(v, 0.f);
            C[(long)gm * ldc + gn] = v;
        }
    }
}

// ================================================================== prep
// f32 [768][768] -> bf16 [768][768] transposed, batched
__global__ void transpose_f2b(const float* __restrict__ src, long sStride,
                              u16* __restrict__ dst, long dStride)
{
    __shared__ float t[32][33];
    int z = blockIdx.z;
    src += (long)z * sStride;
    dst += (long)z * dStride;
    int bx = blockIdx.x * 32, by = blockIdx.y * 32;
    int x = threadIdx.x, y = threadIdx.y;  // 32 x 8
#pragma unroll
    for (int i = 0; i < 32; i += 8)
        t[y + i][x] = src[(long)(by + y + i) * 768 + bx + x];
    __syncthreads();
#pragma unroll
    for (int i = 0; i < 32; i += 8)
        dst[(long)(bx + y + i) * 768 + by + x] = f2b(t[x][y + i]);
}

// combined bias: bc[combo][h*96+j] = sum_d kb_slice[h*96+d] * R[l,e,h,d,j]
__global__ void bias_comb_k(const float* __restrict__ kb, const float* __restrict__ aR,
                            const float* __restrict__ mR, float* __restrict__ bc)
{
    int idx = blockIdx.x * blockDim.x + threadIdx.x;
    if (idx >= 12 * 768) return;
    int combo = idx / 768;
    int x = idx % 768;
    int h = x / 96, j = x % 96;
    int c6 = combo % 6;
    int l = c6 / 3, e = c6 % 3;
    int kind = (combo < 6) ? 0 : 2;
    int st = (e == 1) ? 1 : 0;
    const float* R = ((combo < 6) ? aR : mR) + ((long)(l * 3 + e) * 8 + h) * 9216;
    const float* kbp = kb + ((long)(l * 2 + st) * 4 + kind) * 768 + h * 96;
    float s = 0.f;
#pragma unroll 8
    for (int d = 0; d < 96; d++) s = fmaf(kbp[d], R[d * 96 + j], s);
    bc[idx] = s;
}

// x f32 -> bf16, zero-fill pad rows
__global__ void conv_pad(const float* __restrict__ src, u16* __restrict__ dst,
                         long nReal, long nPad)
{
    long i = blockIdx.x * (long)blockDim.x + threadIdx.x;
    if (i >= nPad) return;
    dst[i] = (i < nReal) ? f2b(src[i]) : (u16)0;
}

// ================================================================== pointwise
__global__ void fill_f32(float* __restrict__ p, float v, long n) {
    long i = blockIdx.x * (long)blockDim.x + threadIdx.x;
    if (i < n) p[i] = v;
}

__global__ void gelu_k(const float* __restrict__ in, u16* __restrict__ out, long n) {
    long i = blockIdx.x * (long)blockDim.x + threadIdx.x;
    if (i < n) {
        float x = in[i];
        out[i] = f2b(0.5f * x * (1.f + erff(x * 0.70710678118654752f)));
    }
}

// out_bf = relu(beta*o + (1-beta)*h); optionally also write f32
__global__ void skip_k(const float* __restrict__ o, const u16* __restrict__ hin,
                       const float* __restrict__ sp, u16* __restrict__ outb,
                       float* __restrict__ outf, long n)
{
    long i = blockIdx.x * (long)blockDim.x + threadIdx.x;
    if (i < n) {
        float beta = 1.f / (1.f + expf(-sp[0]));
        float v = beta * o[i] + (1.f - beta) * b2f(hin[i]);
        v = fmaxf(v, 0.f);
        outb[i] = f2b(v);
        if (outf) outf[i] = v;
    }
}

// ================================================================== edge ops
__device__ __forceinline__ float bdot(u32 a, u32 b, float s) {
    float al = __uint_as_float(a << 16);
    float ah = __uint_as_float(a & 0xffff0000u);
    float bl = __uint_as_float(b << 16);
    float bh = __uint_as_float(b & 0xffff0000u);
    return fmaf(ah, bh, fmaf(al, bl, s));
}

__global__ void edge_logits(const u16* __restrict__ q, const u16* __restrict__ kt,
                            const int* __restrict__ src, const int* __restrict__ dst,
                            const float* __restrict__ prel, float* __restrict__ out,
                            int ne)
{
    int idx = blockIdx.x * blockDim.x + threadIdx.x;
    if (idx >= ne * HEADS) return;
    int e = idx >> 3, h = idx & 7;
    const u16* qr = q + (long)dst[e] * HIDDEN + h * DHEAD;
    const u16* kr = kt + (long)src[e] * HIDDEN + h * DHEAD;
    float s = 0.f;
#pragma unroll
    for (int c = 0; c < 12; c++) {
        uint4 qv = *(const uint4*)(qr + c * 8);
        uint4 kv = *(const uint4*)(kr + c * 8);
        s = bdot(qv.x, kv.x, s);
        s = bdot(qv.y, kv.y, s);
        s = bdot(qv.z, kv.z, s);
        s = bdot(qv.w, kv.w, s);
    }
    out[idx] = s * prel[h] * 0.1020620726159658f;  // 1/sqrt(96)
}

__device__ __forceinline__ void atomicMaxF(float* addr, float val) {
    int* ia = (int*)addr;
    int cur = __float_as_int(*addr);
    while (__int_as_float(cur) < val) {
        int assumed = cur;
        cur = atomicCAS(ia, assumed, __float_as_int(val));
        if (cur == assumed) break;
    }
}

__global__ void seg_max_k(const float* __restrict__ lg, const int* __restrict__ dst,
                          float* __restrict__ dmax, int ne) {
    int idx = blockIdx.x * blockDim.x + threadIdx.x;
    if (idx >= ne * HEADS) return;
    int e = idx >> 3, h = idx & 7;
    atomicMaxF(&dmax[(long)dst[e] * HEADS + h], lg[idx]);
}

__global__ void seg_expsum_k(float* __restrict__ lg, const int* __restrict__ dst,
                             const float* __restrict__ dmax, float* __restrict__ denom,
                             int ne) {
    int idx = blockIdx.x * blockDim.x + threadIdx.x;
    if (idx >= ne * HEADS) return;
    int e = idx >> 3, h = idx & 7;
    float v = expf(lg[idx] - dmax[(long)dst[e] * HEADS + h]);
    lg[idx] = v;
    atomicAdd(&denom[(long)dst[e] * HEADS + h], v);
}

__global__ void seg_norm_k(float* __restrict__ lg, const int* __restrict__ dst,
                           const float* __restrict__ denom, int ne) {
    int idx = blockIdx.x * blockDim.x + threadIdx.x;
    if (idx >= ne * HEADS) return;
    int e = idx >> 3, h = idx & 7;
    lg[idx] = lg[idx] / (denom[(long)dst[e] * HEADS + h] + 1e-16f);
}

__global__ void edge_accum(const float* __restrict__ alpha, const u16* __restrict__ vt,
                           const int* __restrict__ src, const int* __restrict__ dst,
                           float* __restrict__ aggr, int ne)
{
    long idx = blockIdx.x * (long)blockDim.x + threadIdx.x;
    if (idx >= (long)ne * HIDDEN) return;
    int e = (int)(idx / HIDDEN);
    int c = (int)(idx % HIDDEN);
    int h = c / DHEAD;
    float a = alpha[(long)e * HEADS + h];
    float v = b2f(vt[(long)src[e] * HIDDEN + c]);
    atomicAdd(&aggr[(long)dst[e] * HIDDEN + c], a * v);
}

// ================================================================== host
static inline void mfma_bf16out(hipStream_t s, const u16* A, const u16* Wt,
                                const float* bias, u16* Cb, int M, int act) {
    dim3 grid(M / 128, HIDDEN / 128);
    if (act)
        gemm_mfma<0, 1, 1><<<grid, 256, 0, s>>>(A, Wt, bias, nullptr, Cb, M, HIDDEN, HIDDEN);
    else
        gemm_mfma<0, 1, 0><<<grid, 256, 0, s>>>(A, Wt, bias, nullptr, Cb, M, HIDDEN, HIDDEN);
}
static inline void mfma_f32out(hipStream_t s, const u16* A, const u16* Wt,
                               const float* bias, float* Cf, int M) {
    dim3 grid(M / 128, HIDDEN / 128);
    gemm_mfma<1, 0, 0><<<grid, 256, 0, s>>>(A, Wt, bias, Cf, nullptr, M, HIDDEN, HIDDEN);
}

extern "C" void kernel_launch(void* const* d_in, const int* in_sizes, int n_in,
                              void* d_out, int out_size, void* d_ws, size_t ws_size,
                              hipStream_t stream)
{
    const float* x0  = (const float*)d_in[0];
    const float* x1  = (const float*)d_in[1];
    const float* nlW = (const float*)d_in[2];
    const float* nlb = (const float*)d_in[3];
    const float* kW  = (const float*)d_in[4];   // [L,2,4,768,768]
    const float* kb  = (const float*)d_in[5];   // [L,2,4,768]
    const float* skp = (const float*)d_in[6];   // [L,2]
    const float* aR  = (const float*)d_in[7];   // [L,3,8,96,96]
    const float* mR  = (const float*)d_in[8];   // [L,3,8,96,96]
    const float* pR  = (const float*)d_in[9];   // [L,3,8]
    const int* esrc[3] = {(const int*)d_in[10], (const int*)d_in[12], (const int*)d_in[14]};
    const int* edst[3] = {(const int*)d_in[11], (const int*)d_in[13], (const int*)d_in[15]};
    const int EST[3] = {0, 1, 0};
    const int EDT[3] = {0, 0, 1};
    const int EN[3]  = {in_sizes[10], in_sizes[12], in_sizes[14]};

    const int NP = in_sizes[0] / HIDDEN;
    const int NA = in_sizes[1] / HIDDEN;
    const int ns[2]    = {NP, NA};
    const int nspad[2] = {(NP + 127) & ~127, (NA + 127) & ~127};

    // ---------------- workspace (bytes, 256-aligned) ----------------
    char* base = (char*)d_ws;
    size_t off = 0;
    auto alloc = [&](size_t bytes) -> void* {
        void* p = base + off;
        off += (bytes + 255) & ~(size_t)255;
        return p;
    };
    u16* hbf[2] = {(u16*)alloc((size_t)nspad[0] * HIDDEN * 2),
                   (u16*)alloc((size_t)nspad[1] * HIDDEN * 2)};
    u16* qbf[2] = {(u16*)alloc((size_t)nspad[0] * HIDDEN * 2),   // also x-bf16, gelu-bf16
                   (u16*)alloc((size_t)nspad[1] * HIDDEN * 2)};
    u16* ktvbase = (u16*)alloc((size_t)(2 * nspad[0] + nspad[1]) * HIDDEN * 2);
    u16* ktv[3] = {ktvbase, ktvbase + (size_t)nspad[0] * HIDDEN,
                   ktvbase + (size_t)(nspad[0] + nspad[1]) * HIDDEN};
    float* Obuf = (float*)ktvbase;                               // phase-C reuse
    float* aggr[2] = {(float*)alloc((size_t)nspad[0] * HIDDEN * 4),
                      (float*)alloc((size_t)nspad[1] * HIDDEN * 4)};
    float* alphab[3];
    for (int e = 0; e < 3; e++) alphab[e] = (float*)alloc((size_t)EN[e] * HEADS * 4);
    float* dmax  = (float*)alloc((size_t)nspad[0] * HEADS * 4);
    float* denom = (float*)alloc((size_t)nspad[0] * HEADS * 4);
    u16* Wbf     = (u16*)alloc((size_t)22 * HH * 2);   // transposed bf16 weights
    float* Wcomb = (float*)alloc((size_t)12 * HH * 4); // combined f32 weights
    float* bcomb = (float*)alloc((size_t)12 * 768 * 4);
    if (off > ws_size)
        fprintf(stderr, "kernel_launch: ws too small: need %zu have %zu\n", off, ws_size);

    auto wslot = [&](int s) { return Wbf + (size_t)s * HH; };

    // ---------------- weight prep ----------------
    // combined kt/vt weights: Wc = Wk_slice[768x96] @ R[h][96x96], head-batched
    for (int l = 0; l < NLAYERS; l++)
        for (int e = 0; e < 3; e++) {
            int st = EST[e];
            {   // kt (kind 0, aR)
                const float* Ap = kW + ((size_t)(l * 2 + st) * 4 + 0) * HH;
                const float* Wp = aR + ((size_t)(l * 3 + e)) * 8 * 9216;
                float* Cp = Wcomb + (size_t)(l * 3 + e) * HH;
                dim3 g(12, 2, 8);
                gemm_f32<0><<<g, 256, 0, stream>>>(Ap, 768, 96, Wp, 96, 9216,
                                                   nullptr, 0, Cp, 768, 96, 768, 96, 96);
            }
            {   // vt (kind 2, mR)
                const float* Ap = kW + ((size_t)(l * 2 + st) * 4 + 2) * HH;
                const float* Wp = mR + ((size_t)(l * 3 + e)) * 8 * 9216;
                float* Cp = Wcomb + (size_t)(6 + l * 3 + e) * HH;
                dim3 g(12, 2, 8);
                gemm_f32<0><<<g, 256, 0, stream>>>(Ap, 768, 96, Wp, 96, 9216,
                                                   nullptr, 0, Cp, 768, 96, 768, 96, 96);
            }
        }
    bias_comb_k<<<(12 * 768 + 255) / 256, 256, 0, stream>>>(kb, aR, mR, bcomb);

    // transpose-convert weights to bf16 [N][K]
    {
        dim3 b(32, 8);
        dim3 g(24, 24, 2);
        transpose_f2b<<<g, b, 0, stream>>>(nlW, HH, wslot(0), HH);          // node: slots 0,1
        g.z = 4;
        transpose_f2b<<<g, b, 0, stream>>>(kW + (size_t)1 * HH, 4 * (long)HH, wslot(2), HH); // Q: 2..5
        transpose_f2b<<<g, b, 0, stream>>>(kW + (size_t)3 * HH, 4 * (long)HH, wslot(6), HH); // A: 6..9
        g.z = 6;
        transpose_f2b<<<g, b, 0, stream>>>(Wcomb, HH, wslot(10), HH);                // kcomb: 10..15
        transpose_f2b<<<g, b, 0, stream>>>(Wcomb + (size_t)6 * HH, HH, wslot(16), HH); // vcomb: 16..21
    }

    // ---------------- input projection ----------------
    for (int t = 0; t < 2; t++) {
        long nPad = (long)nspad[t] * HIDDEN, nReal = (long)ns[t] * HIDDEN;
        conv_pad<<<(int)((nPad + 255) / 256), 256, 0, stream>>>(t ? x1 : x0, qbf[t], nReal, nPad);
        mfma_bf16out(stream, qbf[t], wslot(t), nlb + (size_t)t * 768, hbf[t], nspad[t], 1);
    }

    // ---------------- layers ----------------
    for (int l = 0; l < NLAYERS; l++) {
        // phase A: Q + kt projections, logits, segment softmax
        for (int t = 0; t < 2; t++)
            mfma_bf16out(stream, hbf[t], wslot(2 + l * 2 + t),
                         kb + ((size_t)(l * 2 + t) * 4 + 1) * 768, qbf[t], nspad[t], 0);
        for (int e = 0; e < 3; e++) {
            int st = EST[e], dt = EDT[e], Ne = EN[e];
            mfma_bf16out(stream, hbf[st], wslot(10 + l * 3 + e),
                         bcomb + (size_t)(l * 3 + e) * 768, ktv[e], nspad[st], 0);
            int nthr = Ne * HEADS;
            edge_logits<<<(nthr + 255) / 256, 256, 0, stream>>>(
                qbf[dt], ktv[e], esrc[e], edst[e],
                pR + ((size_t)l * 3 + e) * HEADS, alphab[e], Ne);
            long nd = (long)ns[dt] * HEADS;
            fill_f32<<<(int)((nd + 255) / 256), 256, 0, stream>>>(dmax, -INFINITY, nd);
            hipMemsetAsync(denom, 0, nd * sizeof(float), stream);
            seg_max_k<<<(nthr + 255) / 256, 256, 0, stream>>>(alphab[e], edst[e], dmax, Ne);
            seg_expsum_k<<<(nthr + 255) / 256, 256, 0, stream>>>(alphab[e], edst[e], dmax, denom, Ne);
            seg_norm_k<<<(nthr + 255) / 256, 256, 0, stream>>>(alphab[e], edst[e], denom, Ne);
        }
        // phase B: vt projections + weighted scatter-add
        for (int t = 0; t < 2; t++)
            hipMemsetAsync(aggr[t], 0, (size_t)nspad[t] * HIDDEN * 4, stream);
        for (int e = 0; e < 3; e++) {
            int st = EST[e], dt = EDT[e];
            mfma_bf16out(stream, hbf[st], wslot(16 + l * 3 + e),
                         bcomb + (size_t)(6 + l * 3 + e) * 768, ktv[e], nspad[st], 0);
            long tot = (long)EN[e] * HIDDEN;
            edge_accum<<<(int)((tot + 255) / 256), 256, 0, stream>>>(
                alphab[e], ktv[e], esrc[e], edst[e], aggr[dt], EN[e]);
        }
        // phase C: gelu -> A-projection -> skip/relu
        for (int t = 0; t < 2; t++) {
            long nPad = (long)nspad[t] * HIDDEN, nReal = (long)ns[t] * HIDDEN;
            gelu_k<<<(int)((nPad + 255) / 256), 256, 0, stream>>>(aggr[t], qbf[t], nPad);
            mfma_f32out(stream, qbf[t], wslot(6 + l * 2 + t),
                        kb + ((size_t)(l * 2 + t) * 4 + 3) * 768, Obuf, nspad[t]);
            float* outf = (l == NLAYERS - 1)
                        ? ((float*)d_out + (t == 0 ? 0 : (size_t)NP * HIDDEN))
                        : nullptr;
            skip_k<<<(int)((nReal + 255) / 256), 256, 0, stream>>>(
                Obuf, hbf[t], skp + (size_t)l * 2 + t, hbf[t], outf, nReal);
        }
    }
}